// Round 2
// baseline (59.287 us; speedup 1.0000x reference)
//
#include <hip/hip_runtime.h>

// GAE: A_t = delta_t + (gamma*lam) * A_{t+1}, backward over S; returns = A + values.
// Constant-coefficient linear recurrence -> exact parallel weighted suffix scan.
// All-register version: no LDS staging (R0 had 32-way bank conflicts on the
// stride-16 chunk accesses and a 33KB LDS occupancy cap).

#define GAMMA 0.99f
#define LAM   0.95f

constexpr int S_LEN = 4096;
constexpr int TPB   = 256;
constexpr int CHUNK = S_LEN / TPB; // 16 elements per thread, contiguous

__global__ __launch_bounds__(TPB) void gae_kernel(const float* __restrict__ rewards,
                                                  const float* __restrict__ values,
                                                  const float* __restrict__ next_values,
                                                  float* __restrict__ out, int B) {
    __shared__ float waveT[4];

    const int b   = blockIdx.x;
    const int tid = threadIdx.x;
    const float c = GAMMA * LAM;

    const size_t rowoff = (size_t)b * S_LEN + (size_t)tid * CHUNK;
    const float* vrow = values  + rowoff;
    const float* rrow = rewards + rowoff;

    // ---- direct global loads: 4+4 float4 per thread (wave covers contiguous 16KB) ----
    float4 v4[4], r4[4];
#pragma unroll
    for (int j = 0; j < 4; ++j) v4[j] = ((const float4*)vrow)[j];
#pragma unroll
    for (int j = 0; j < 4; ++j) r4[j] = ((const float4*)rrow)[j];
    // chunk-boundary neighbor: next chunk's first value (L1 hit), or bootstrap
    const float vtail = (tid == TPB - 1) ? next_values[b] : vrow[CHUNK];

    float v[CHUNK + 1];
#pragma unroll
    for (int j = 0; j < 4; ++j) {
        v[4 * j + 0] = v4[j].x; v[4 * j + 1] = v4[j].y;
        v[4 * j + 2] = v4[j].z; v[4 * j + 3] = v4[j].w;
    }
    v[CHUNK] = vtail;
    float r[CHUNK];
#pragma unroll
    for (int j = 0; j < 4; ++j) {
        r[4 * j + 0] = r4[j].x; r[4 * j + 1] = r4[j].y;
        r[4 * j + 2] = r4[j].z; r[4 * j + 3] = r4[j].w;
    }

    // ---- per-thread local backward scan over the 16-element chunk ----
    float a[CHUNK];
    float acc = 0.f;
#pragma unroll
    for (int li = CHUNK - 1; li >= 0; --li) {
        float delta = fmaf(GAMMA, v[li + 1], r[li]) - v[li];
        acc = fmaf(c, acc, delta);
        a[li] = acc;
    }
    float x = acc; // chunk value assuming zero incoming carry

    // q = c^CHUNK
    float q = 1.f;
#pragma unroll
    for (int k = 0; k < CHUNK; ++k) q *= c;

    // ---- intra-wave weighted suffix scan (64 lanes, factor q) ----
    const int lane = tid & 63;
    const int wave = tid >> 6;
    float qs[6];      // q^(2^k), saved for binary exponentiation
    float qd = q;
#pragma unroll
    for (int dlog = 0; dlog < 6; ++dlog) {
        int d = 1 << dlog;
        qs[dlog] = qd;
        float other = __shfl_down(x, d);
        if (lane + d < 64) x = fmaf(qd, other, x);
        qd *= qd;       // q^d -> q^(2d)
    }
    const float Q = qd; // q^64

    // ---- cross-wave combine: wave totals -> carries ----
    if (lane == 0) waveT[wave] = x;
    __syncthreads();
    float t1 = waveT[1], t2 = waveT[2], t3 = waveT[3];
    float F3 = t3;
    float F2 = fmaf(Q, F3, t2);
    float F1 = fmaf(Q, F2, t1);
    // carry entering this wave's tail (A at start of wave w+1); F4 = 0
    float carry_wave = (wave == 3) ? 0.f : (wave == 2 ? F3 : (wave == 1 ? F2 : F1));

    // C = A at start of chunk tid+1 = W[lane+1] + q^(63-lane) * carry_wave
    float Wnext = __shfl_down(x, 1);
    int e = 63 - lane;
    float qp = 1.f;
#pragma unroll
    for (int k = 0; k < 6; ++k) qp *= ((e >> k) & 1) ? qs[k] : 1.f;
    float C = (lane == 63) ? carry_wave : fmaf(qp, carry_wave, Wnext);

    // ---- apply carry into local chunk: A[li] += c^(CHUNK-li) * C ----
    float p = c;
#pragma unroll
    for (int li = CHUNK - 1; li >= 0; --li) {
        a[li] = fmaf(p, C, a[li]);
        p *= c;
    }

    // ---- direct stores: advantages and returns (values still in registers) ----
    float* adv_row = out + rowoff;
    float* ret_row = out + (size_t)B * S_LEN + rowoff;
#pragma unroll
    for (int j = 0; j < 4; ++j) {
        float4 av = make_float4(a[4 * j + 0], a[4 * j + 1], a[4 * j + 2], a[4 * j + 3]);
        ((float4*)adv_row)[j] = av;
        float4 rv = make_float4(av.x + v[4 * j + 0], av.y + v[4 * j + 1],
                                av.z + v[4 * j + 2], av.w + v[4 * j + 3]);
        ((float4*)ret_row)[j] = rv;
    }
}

extern "C" void kernel_launch(void* const* d_in, const int* in_sizes, int n_in,
                              void* d_out, int out_size, void* d_ws, size_t ws_size,
                              hipStream_t stream) {
    const float* rewards     = (const float*)d_in[0];
    const float* values      = (const float*)d_in[1];
    const float* next_values = (const float*)d_in[2];
    float* out = (float*)d_out;
    const int B = in_sizes[2];             // 4096
    gae_kernel<<<B, TPB, 0, stream>>>(rewards, values, next_values, out, B);
}

// Round 3
// 45.341 us; speedup vs baseline: 1.3076x; 1.3076x over previous
//
#include <hip/hip_runtime.h>

// GAE: A_t = delta_t + (gamma*lam)*A_{t+1} backward over S=4096; returns = A + values.
// Exact parallel weighted suffix scan, all-register, fully wave-coalesced float4 I/O.
// Decomposition: row = 4 segments x 1024; thread owns 4 contiguous elts per segment
// (one float4 -> per-instruction the wave covers contiguous 1024B). 16 chunk totals
// (256 elts each) combined by a redundant per-wave 16-entry shuffle scan; 1 barrier.

#define GAMMA 0.99f
#define LAM   0.95f

constexpr int S_LEN = 4096;
constexpr int TPB   = 256;
constexpr int NSEG  = 4;      // segments of 1024 = TPB*4

__global__ __launch_bounds__(TPB) void gae_kernel(const float* __restrict__ rewards,
                                                  const float* __restrict__ values,
                                                  const float* __restrict__ next_values,
                                                  float* __restrict__ out, int B) {
    __shared__ float Tlds[16];

    const int b    = blockIdx.x;
    const int tid  = threadIdx.x;
    const int lane = tid & 63;
    const int w    = tid >> 6;
    const float c  = GAMMA * LAM;
    const float q4 = c * c * c * c;

    const float* vrow = values  + (size_t)b * S_LEN;
    const float* rrow = rewards + (size_t)b * S_LEN;
    const float  nv   = next_values[b];

    // ---- load all segments: wave-contiguous float4 (1024B per instruction) ----
    float4 v4[NSEG], r4[NSEG];
    float  vn[NSEG];
#pragma unroll
    for (int s = 0; s < NSEG; ++s) {
        const int g0 = s * 1024 + 4 * tid;
        v4[s] = *(const float4*)(vrow + g0);
        r4[s] = *(const float4*)(rrow + g0);
    }
#pragma unroll
    for (int s = 0; s < NSEG; ++s) {
        const int g4 = s * 1024 + 4 * tid + 4;
        if (s == NSEG - 1 && tid == TPB - 1) vn[s] = nv;       // bootstrap
        else                                 vn[s] = vrow[g4]; // cache-hot neighbor
    }

    // ---- per segment: local 4-elt backward scan + 64-lane weighted suffix scan ----
    float a0[NSEG], a1[NSEG], a2[NSEG], a3[NSEG]; // local suffix values (zero carry)
    float Wn[NSEG];                               // x(lane+1) within wave
    float Tk = 0.f;                               // chunk total held by lane s
    float qs[6];                                  // q4^(2^k), same every segment
    {
        float qd = q4;
#pragma unroll
        for (int k = 0; k < 6; ++k) { qs[k] = qd; qd *= qd; }
    }
    const float Q256 = qs[5] * qs[5]; // c^256

#pragma unroll
    for (int s = 0; s < NSEG; ++s) {
        // deltas
        float d3 = fmaf(GAMMA, vn[s],   r4[s].w) - v4[s].w;
        float d2 = fmaf(GAMMA, v4[s].w, r4[s].z) - v4[s].z;
        float d1 = fmaf(GAMMA, v4[s].z, r4[s].y) - v4[s].y;
        float d0 = fmaf(GAMMA, v4[s].y, r4[s].x) - v4[s].x;
        // local backward scan
        float t3 = d3;
        float t2 = fmaf(c, t3, d2);
        float t1 = fmaf(c, t2, d1);
        float t0 = fmaf(c, t1, d0);
        a3[s] = t3; a2[s] = t2; a1[s] = t1; a0[s] = t0;

        // intra-wave weighted suffix scan, factor q4
        float x = t0;
#pragma unroll
        for (int dlog = 0; dlog < 6; ++dlog) {
            int d = 1 << dlog;
            float other = __shfl_down(x, d);
            if (lane + d < 64) x = fmaf(qs[dlog], other, x);
        }
        Wn[s] = __shfl_down(x, 1);        // x(lane+1); garbage at lane 63 (unused)
        float tb = __shfl(x, 0);          // chunk total T_{m = s*4+w}
        if (lane == s) Tk = tb;
    }

    // ---- cross-chunk combine: 16 totals, factor c^256, redundant per-wave scan ----
    if (lane < NSEG) Tlds[lane * 4 + w] = Tk;
    __syncthreads();
    float tv = (lane < 16) ? Tlds[lane] : 0.f;
    {
        float Qd = Q256;
#pragma unroll
        for (int dlog = 0; dlog < 4; ++dlog) {
            int d = 1 << dlog;
            float other = __shfl_down(tv, d);
            if (lane + d < 16) tv = fmaf(Qd, other, tv);
            Qd *= Qd;
        }
    }
    // tv(lane=m) = S_m = suffix of chunk totals from chunk m

    // q4^(63-lane) for the wave-carry weight (binary exponentiation)
    float qp = 1.f;
    {
        int e = 63 - lane;
#pragma unroll
        for (int k = 0; k < 6; ++k) if ((e >> k) & 1) qp *= qs[k];
    }

    // ---- apply carries, store (coalesced float4) ----
    float* adv_row = out + (size_t)b * S_LEN;
    float* ret_row = out + (size_t)B * S_LEN + (size_t)b * S_LEN;
    const float c2 = c * c, c3 = c2 * c;
#pragma unroll
    for (int s = 0; s < NSEG; ++s) {
        const int m = s * 4 + w;
        float Cm = (m == 15) ? 0.f : __shfl(tv, m + 1);        // carry into chunk m
        float ct = (lane == 63) ? Cm : fmaf(qp, Cm, Wn[s]);    // carry into thread
        float o3 = fmaf(c,  ct, a3[s]);
        float o2 = fmaf(c2, ct, a2[s]);
        float o1 = fmaf(c3, ct, a1[s]);
        float o0 = fmaf(q4, ct, a0[s]);
        const int g0 = s * 1024 + 4 * tid;
        float4 av = make_float4(o0, o1, o2, o3);
        *(float4*)(adv_row + g0) = av;
        float4 rv = make_float4(av.x + v4[s].x, av.y + v4[s].y,
                                av.z + v4[s].z, av.w + v4[s].w);
        *(float4*)(ret_row + g0) = rv;
    }
}

extern "C" void kernel_launch(void* const* d_in, const int* in_sizes, int n_in,
                              void* d_out, int out_size, void* d_ws, size_t ws_size,
                              hipStream_t stream) {
    const float* rewards     = (const float*)d_in[0];
    const float* values      = (const float*)d_in[1];
    const float* next_values = (const float*)d_in[2];
    float* out = (float*)d_out;
    const int B = in_sizes[2];   // 4096
    gae_kernel<<<B, TPB, 0, stream>>>(rewards, values, next_values, out, B);
}

// Round 5
// 43.896 us; speedup vs baseline: 1.3506x; 1.0329x over previous
//
#include <hip/hip_runtime.h>

// GAE: A_t = delta_t + (gamma*lam)*A_{t+1} backward over S=4096; returns = A + values.
// Exact parallel weighted suffix scan, all-register, fully wave-coalesced float4 I/O.
// R4: nontemporal stores via native ext_vector float4 (HIP float4 class is rejected
// by __builtin_nontemporal_store). Writes are pure streaming (never re-read) ->
// bypass cache allocation to keep the 128MiB of inputs L3-resident (R2 showed
// FETCH_SIZE = 64MiB of 128MiB: write allocation was evicting input lines).

#define GAMMA 0.99f
#define LAM   0.95f

typedef float fvec4 __attribute__((ext_vector_type(4)));

constexpr int S_LEN = 4096;
constexpr int TPB   = 256;
constexpr int NSEG  = 4;      // segments of 1024 = TPB*4

__global__ __launch_bounds__(TPB) void gae_kernel(const float* __restrict__ rewards,
                                                  const float* __restrict__ values,
                                                  const float* __restrict__ next_values,
                                                  float* __restrict__ out, int B) {
    __shared__ float Tlds[16];

    const int b    = blockIdx.x;
    const int tid  = threadIdx.x;
    const int lane = tid & 63;
    const int w    = tid >> 6;
    const float c  = GAMMA * LAM;
    const float q4 = c * c * c * c;

    const float* vrow = values  + (size_t)b * S_LEN;
    const float* rrow = rewards + (size_t)b * S_LEN;
    const float  nv   = next_values[b];

    // ---- load all segments: wave-contiguous float4 (1024B per instruction) ----
    fvec4 v4[NSEG], r4[NSEG];
    float vn[NSEG];
#pragma unroll
    for (int s = 0; s < NSEG; ++s) {
        const int g0 = s * 1024 + 4 * tid;
        v4[s] = *(const fvec4*)(vrow + g0);
        r4[s] = *(const fvec4*)(rrow + g0);
    }
#pragma unroll
    for (int s = 0; s < NSEG; ++s) {
        const int g4 = s * 1024 + 4 * tid + 4;
        if (s == NSEG - 1 && tid == TPB - 1) vn[s] = nv;       // bootstrap
        else                                 vn[s] = vrow[g4]; // cache-hot neighbor
    }

    // ---- per segment: local 4-elt backward scan + 64-lane weighted suffix scan ----
    float a0[NSEG], a1[NSEG], a2[NSEG], a3[NSEG]; // local suffix values (zero carry)
    float Wn[NSEG];                               // x(lane+1) within wave
    float Tk = 0.f;                               // chunk total held by lane s
    float qs[6];                                  // q4^(2^k), same every segment
    {
        float qd = q4;
#pragma unroll
        for (int k = 0; k < 6; ++k) { qs[k] = qd; qd *= qd; }
    }
    const float Q256 = qs[5] * qs[5]; // c^256

#pragma unroll
    for (int s = 0; s < NSEG; ++s) {
        // deltas
        float d3 = fmaf(GAMMA, vn[s],    r4[s].w) - v4[s].w;
        float d2 = fmaf(GAMMA, v4[s].w,  r4[s].z) - v4[s].z;
        float d1 = fmaf(GAMMA, v4[s].z,  r4[s].y) - v4[s].y;
        float d0 = fmaf(GAMMA, v4[s].y,  r4[s].x) - v4[s].x;
        // local backward scan
        float t3 = d3;
        float t2 = fmaf(c, t3, d2);
        float t1 = fmaf(c, t2, d1);
        float t0 = fmaf(c, t1, d0);
        a3[s] = t3; a2[s] = t2; a1[s] = t1; a0[s] = t0;

        // intra-wave weighted suffix scan, factor q4
        float x = t0;
#pragma unroll
        for (int dlog = 0; dlog < 6; ++dlog) {
            int d = 1 << dlog;
            float other = __shfl_down(x, d);
            if (lane + d < 64) x = fmaf(qs[dlog], other, x);
        }
        Wn[s] = __shfl_down(x, 1);        // x(lane+1); garbage at lane 63 (unused)
        float tb = __shfl(x, 0);          // chunk total T_{m = s*4+w}
        if (lane == s) Tk = tb;
    }

    // ---- cross-chunk combine: 16 totals, factor c^256, redundant per-wave scan ----
    if (lane < NSEG) Tlds[lane * 4 + w] = Tk;
    __syncthreads();
    float tv = (lane < 16) ? Tlds[lane] : 0.f;
    {
        float Qd = Q256;
#pragma unroll
        for (int dlog = 0; dlog < 4; ++dlog) {
            int d = 1 << dlog;
            float other = __shfl_down(tv, d);
            if (lane + d < 16) tv = fmaf(Qd, other, tv);
            Qd *= Qd;
        }
    }
    // tv(lane=m) = S_m = suffix of chunk totals from chunk m

    // q4^(63-lane) for the wave-carry weight (binary exponentiation)
    float qp = 1.f;
    {
        int e = 63 - lane;
#pragma unroll
        for (int k = 0; k < 6; ++k) if ((e >> k) & 1) qp *= qs[k];
    }

    // ---- apply carries, store (coalesced nontemporal float4) ----
    float* adv_row = out + (size_t)b * S_LEN;
    float* ret_row = out + (size_t)B * S_LEN + (size_t)b * S_LEN;
    const float c2 = c * c, c3 = c2 * c;
#pragma unroll
    for (int s = 0; s < NSEG; ++s) {
        const int m = s * 4 + w;
        float Cm = (m == 15) ? 0.f : __shfl(tv, m + 1);        // carry into chunk m
        float ct = (lane == 63) ? Cm : fmaf(qp, Cm, Wn[s]);    // carry into thread
        float o3 = fmaf(c,  ct, a3[s]);
        float o2 = fmaf(c2, ct, a2[s]);
        float o1 = fmaf(c3, ct, a1[s]);
        float o0 = fmaf(q4, ct, a0[s]);
        const int g0 = s * 1024 + 4 * tid;
        fvec4 av; av.x = o0; av.y = o1; av.z = o2; av.w = o3;
        fvec4 rv = av + v4[s];
        __builtin_nontemporal_store(av, (fvec4*)(adv_row + g0));
        __builtin_nontemporal_store(rv, (fvec4*)(ret_row + g0));
    }
}

extern "C" void kernel_launch(void* const* d_in, const int* in_sizes, int n_in,
                              void* d_out, int out_size, void* d_ws, size_t ws_size,
                              hipStream_t stream) {
    const float* rewards     = (const float*)d_in[0];
    const float* values      = (const float*)d_in[1];
    const float* next_values = (const float*)d_in[2];
    float* out = (float*)d_out;
    const int B = in_sizes[2];   // 4096
    gae_kernel<<<B, TPB, 0, stream>>>(rewards, values, next_values, out, B);
}